// Round 4
// baseline (168.703 us; speedup 1.0000x reference)
//
#include <hip/hip_runtime.h>
#include <math.h>

// One wave = 64 batch elements, fully wave-private (no barriers).
// Phase A (per lane): closed-form 3x3 symmetric eigenvalues + layer0 -> write
//   3 activation columns (f16) + 1 zero column per element into LDS, d-major,
//   [col][24 f16] (48 B stride).
// Phase B (per wave): two 23x23 permutation-equivariant layers as MFMA GEMMs
//   (16x16x32 f16): Y1 = Wi*G, Y2 = Ws*G; sum-path term = butterfly-sum of Y2
//   over each element's 4-lane column group (3 data cols + zero col);
//   relu(Y1 + t + bias) -> f16 -> same LDS cols in place.
// Phase C (per lane): read 3 cols back, layer3 + Newton divided-difference
//   spectral reconstruction in f32 (no eigenvectors needed).

#define MLP_W 23

typedef _Float16 h8 __attribute__((ext_vector_type(8)));
typedef _Float16 h4 __attribute__((ext_vector_type(4)));
typedef float    f4 __attribute__((ext_vector_type(4)));

__device__ __forceinline__ float sinv(float d) {
    // guarded inverse: exact-tie eigenvalues give exact-tie MLP outputs, so the
    // 0/0 limit value never affects p(X) on the actual spectrum.
    return (fabsf(d) > 1e-20f) ? (1.0f / d) : 0.0f;
}

__device__ __forceinline__ f4 mfma16(h8 a, h8 b, f4 c) {
    return __builtin_amdgcn_mfma_f32_16x16x32_f16(a, b, c, 0, 0, 0);
}

__global__ __launch_bounds__(256, 3)
void svh_kernel(const float* __restrict__ x,
                const float* __restrict__ wi0, const float* __restrict__ ws0, const float* __restrict__ b0,
                const float* __restrict__ wi1, const float* __restrict__ ws1, const float* __restrict__ b1,
                const float* __restrict__ wi2, const float* __restrict__ ws2, const float* __restrict__ b2,
                const float* __restrict__ wi3, const float* __restrict__ ws3, const float* __restrict__ b3,
                float* __restrict__ out, int B)
{
    __shared__ __align__(16) _Float16 smem[4][256 * 24];
    const int lane = threadIdx.x & 63;
    const int wv   = threadIdx.x >> 6;
    _Float16* S = smem[wv];

    const int n = lane & 15;   // col-within-tile / A row index
    const int q = lane >> 4;   // quad: k-chunk selector

    // ---- one-time: A fragments (weights -> f16) and per-lane bias vectors ----
    // A[m][k]: m = n + 16*tile (output channel), k = 8*q + j (input channel)
    h8 Awi1[2], Aws1[2], Awi2[2], Aws2[2];
    float bv1[8], bv2[8];   // rows 4q+r (tile0), 16+4q+r (tile1)
#pragma unroll
    for (int t = 0; t < 2; ++t) {
        int o = n + 16 * t;
#pragma unroll
        for (int j = 0; j < 8; ++j) {
            int c = 8 * q + j;
            bool v = (o < MLP_W) && (c < MLP_W);
            Awi1[t][j] = (_Float16)(v ? wi1[o * MLP_W + c] : 0.0f);
            Aws1[t][j] = (_Float16)(v ? ws1[o * MLP_W + c] : 0.0f);
            Awi2[t][j] = (_Float16)(v ? wi2[o * MLP_W + c] : 0.0f);
            Aws2[t][j] = (_Float16)(v ? ws2[o * MLP_W + c] : 0.0f);
        }
    }
#pragma unroll
    for (int r = 0; r < 4; ++r) {
        int r0 = 4 * q + r, r1 = 16 + 4 * q + r;
        bv1[r]     = (r0 < MLP_W) ? b1[r0] : 0.0f;
        bv1[4 + r] = (r1 < MLP_W) ? b1[r1] : 0.0f;
        bv2[r]     = (r0 < MLP_W) ? b2[r0] : 0.0f;
        bv2[4 + r] = (r1 < MLP_W) ? b2[r1] : 0.0f;
    }

    // ---- Phase A: eigenvalues + layer0, stage columns to LDS ----
    const int e = (blockIdx.x * 4 + wv) * 64 + lane;
    float x00 = 0.f, x01 = 0.f, x02 = 0.f, x11 = 0.f, x12 = 0.f, x22 = 0.f;
    float la = 0.f, lb = 0.f, lc = 0.f;

    if (e < B) {
        const float* xp = x + (size_t)e * 9;
        x00 = xp[0]; x01 = xp[1]; x02 = xp[2];
        x11 = xp[4]; x12 = xp[5]; x22 = xp[8];

        // closed-form symmetric 3x3 eigenvalues (trigonometric method)
        float qq  = (x00 + x11 + x22) * (1.0f / 3.0f);
        float a00 = x00 - qq, a11 = x11 - qq, a22 = x22 - qq;
        float p1  = x01 * x01 + x02 * x02 + x12 * x12;
        float p2  = a00 * a00 + a11 * a11 + a22 * a22 + 2.0f * p1;
        float p   = sqrtf(p2 * (1.0f / 6.0f));
        float ip  = sinv(p);
        float d00 = a00 * ip, d11 = a11 * ip, d22 = a22 * ip;
        float c01 = x01 * ip, c02 = x02 * ip, c12 = x12 * ip;
        float detB = d00 * (d11 * d22 - c12 * c12)
                   - c01 * (c01 * d22 - c12 * c02)
                   + c02 * (c01 * c12 - d11 * c02);
        float r = 0.5f * detB;
        r = fminf(1.0f, fmaxf(-1.0f, r));
        float phi = acosf(r) * (1.0f / 3.0f);
        float cph = __cosf(phi);
        float sph = sqrtf(fmaxf(0.0f, 1.0f - cph * cph));
        const float SQ3 = 1.7320508075688772f;
        lc = qq + 2.0f * p * cph;
        la = qq - p * cph - SQ3 * p * sph;
        lb = qq - p * cph + SQ3 * p * sph;

        // layer0 (ic = 1): h[c][d] = relu(wi0[c]*lam_d + ws0[c]*Sum + b0[c])
        float h[MLP_W][3];
        float Ssum = la + lb + lc;
#pragma unroll
        for (int c = 0; c < MLP_W; ++c) {
            float wi = wi0[c];
            float u  = fmaf(ws0[c], Ssum, b0[c]);
            h[c][0] = fmaxf(0.0f, fmaf(wi, la, u));
            h[c][1] = fmaxf(0.0f, fmaf(wi, lb, u));
            h[c][2] = fmaxf(0.0f, fmaf(wi, lc, u));
        }

        // write cols d=0..2 (p = 64*d + lane) and zero col (p = 192 + lane)
#pragma unroll
        for (int d = 0; d < 3; ++d) {
            _Float16* cp = S + (64 * d + lane) * 24;
#pragma unroll
            for (int i = 0; i < 3; ++i) {
                h8 v;
#pragma unroll
                for (int j = 0; j < 8; ++j) {
                    int c = 8 * i + j;
                    v[j] = (_Float16)((c < MLP_W) ? h[c][d] : 0.0f);
                }
                *(h8*)(cp + 8 * i) = v;
            }
        }
        {
            h8 z = {};
            _Float16* cp = S + (192 + lane) * 24;
            *(h8*)(cp)      = z;
            *(h8*)(cp + 8)  = z;
            *(h8*)(cp + 16) = z;
        }
    } else {
        // keep LDS defined for MFMA even on (impossible) tail
        h8 z = {};
#pragma unroll
        for (int d = 0; d < 4; ++d) {
            _Float16* cp = S + (64 * d + lane) * 24;
            *(h8*)(cp) = z; *(h8*)(cp + 8) = z; *(h8*)(cp + 16) = z;
        }
    }

    // ---- Phase B: two equivariant layers via MFMA, in place ----
    const int   acol = n >> 2;                    // element-within-tile
    const float msk  = ((n & 3) == 3) ? 0.0f : 1.0f;  // zero the 4th col on write

    auto run_layer = [&](h8 Ai0, h8 Ai1, h8 As0, h8 As1, const float* bv) {
#pragma unroll
        for (int t = 0; t < 16; ++t) {
            int p   = 64 * (n & 3) + 4 * t + acol;        // physical col
            int off = (q == 3) ? 0 : (p * 24 + 8 * q);    // q==3: safe addr, A is 0 there
            h8 bf = *(const h8*)(S + off);
            f4 z = {};
            f4 c0 = mfma16(Ai0, bf, z);
            f4 c1 = mfma16(Ai1, bf, z);
            f4 d0 = mfma16(As0, bf, z);
            f4 d1 = mfma16(As1, bf, z);
            float y[8];
#pragma unroll
            for (int r = 0; r < 4; ++r) {
                float t0 = d0[r];
                t0 += __shfl_xor(t0, 1);
                t0 += __shfl_xor(t0, 2);
                float t1 = d1[r];
                t1 += __shfl_xor(t1, 1);
                t1 += __shfl_xor(t1, 2);
                y[r]     = fmaxf(0.0f, c0[r] + t0 + bv[r])     * msk;
                y[4 + r] = fmaxf(0.0f, c1[r] + t1 + bv[4 + r]) * msk;
            }
            _Float16* cp = S + p * 24;
            h4 w0, w1;
#pragma unroll
            for (int r = 0; r < 4; ++r) {
                w0[r] = (_Float16)y[r];
                w1[r] = (_Float16)y[4 + r];
            }
            *(h4*)(cp + 4 * q) = w0;                 // k rows 4q..4q+3
            if (q < 2) *(h4*)(cp + 16 + 4 * q) = w1; // k rows 16+4q..19+4q (<=23)
        }
    };
    run_layer(Awi1[0], Awi1[1], Aws1[0], Aws1[1], bv1);
    run_layer(Awi2[0], Awi2[1], Aws2[0], Aws2[1], bv2);

    // ---- Phase C: layer3 + spectral reconstruction ----
    if (e < B) {
        float gg[3][MLP_W];
#pragma unroll
        for (int d = 0; d < 3; ++d) {
            const _Float16* cp = S + (64 * d + lane) * 24;
#pragma unroll
            for (int i = 0; i < 3; ++i) {
                h8 v = *(const h8*)(cp + 8 * i);
#pragma unroll
                for (int j = 0; j < 8; ++j) {
                    int c = 8 * i + j;
                    if (c < MLP_W) gg[d][c] = (float)v[j];
                }
            }
        }

        float a0 = 0.0f, a1 = 0.0f, a2 = 0.0f, as = b3[0];
#pragma unroll
        for (int c = 0; c < MLP_W; ++c) {
            float t0 = gg[0][c], t1 = gg[1][c], t2 = gg[2][c];
            float sc = t0 + t1 + t2;
            float wi = wi3[c];
            a0 = fmaf(wi, t0, a0);
            a1 = fmaf(wi, t1, a1);
            a2 = fmaf(wi, t2, a2);
            as = fmaf(ws3[c], sc, as);
        }
        float eva = a0 + as;   // value at la
        float evb = a1 + as;   // value at lb
        float evc = a2 + as;   // value at lc

        // Newton divided differences; out = eva*I + g1*(X-la I) + c2*(X-la I)(X-lb I)
        float g1 = (evb - eva) * sinv(lb - la);
        float g2 = (evc - evb) * sinv(lc - lb);
        float c2 = (g2 - g1) * sinv(lc - la);

        float m100 = x00 - la, m111 = x11 - la, m122 = x22 - la;
        float m200 = x00 - lb, m211 = x11 - lb, m222 = x22 - lb;

        float P00 = m100 * m200 + x01 * x01 + x02 * x02;
        float P01 = m100 * x01 + x01 * m211 + x02 * x12;
        float P02 = m100 * x02 + x01 * x12 + x02 * m222;
        float P11 = x01 * x01 + m111 * m211 + x12 * x12;
        float P12 = x01 * x02 + m111 * x12 + x12 * m222;
        float P22 = x02 * x02 + x12 * x12 + m122 * m222;

        float o00 = fmaf(g1, m100, eva) + c2 * P00;
        float o01 = g1 * x01 + c2 * P01;
        float o02 = g1 * x02 + c2 * P02;
        float o11 = fmaf(g1, m111, eva) + c2 * P11;
        float o12 = g1 * x12 + c2 * P12;
        float o22 = fmaf(g1, m122, eva) + c2 * P22;

        float* op = out + (size_t)e * 9;
        op[0] = o00; op[1] = o01; op[2] = o02;
        op[3] = o01; op[4] = o11; op[5] = o12;
        op[6] = o02; op[7] = o12; op[8] = o22;
    }
}

extern "C" void kernel_launch(void* const* d_in, const int* in_sizes, int n_in,
                              void* d_out, int out_size, void* d_ws, size_t ws_size,
                              hipStream_t stream) {
    const float* x   = (const float*)d_in[0];
    const float* wi0 = (const float*)d_in[1];
    const float* ws0 = (const float*)d_in[2];
    const float* b0  = (const float*)d_in[3];
    const float* wi1 = (const float*)d_in[4];
    const float* ws1 = (const float*)d_in[5];
    const float* b1  = (const float*)d_in[6];
    const float* wi2 = (const float*)d_in[7];
    const float* ws2 = (const float*)d_in[8];
    const float* b2  = (const float*)d_in[9];
    const float* wi3 = (const float*)d_in[10];
    const float* ws3 = (const float*)d_in[11];
    const float* b3  = (const float*)d_in[12];

    int B = in_sizes[0] / 9;
    float* out = (float*)d_out;

    int blocks = (B + 255) / 256;   // 256 elements per block (4 waves x 64)
    hipLaunchKernelGGL(svh_kernel, dim3(blocks), dim3(256), 0, stream,
                       x, wi0, ws0, b0, wi1, ws1, b1, wi2, ws2, b2, wi3, ws3, b3,
                       out, B);
}